// Round 7
// baseline (2623.359 us; speedup 1.0000x reference)
//
#include <hip/hip_runtime.h>
#include <hip/hip_bf16.h>

#define N_ 307
#define B_ 64
#define T_ 12
#define H_ 64
#define E_ 10
#define CH_ 14
#define HM_ 16
#define I2_ 66   // 2*DIN + H
#define GO_ 128  // 2*H
#define UO_ 64
#define QG_ (2 * I2_ * GO_)  // 16896
#define QU_ (2 * I2_ * UO_)  // 8448
#define TBN_ (T_ * B_ * N_)  // 235776
#define WMP_ 320             // Wm row padded length (bf16)

__device__ __forceinline__ float wsum(float v) {
    #pragma unroll
    for (int off = 32; off; off >>= 1) v += __shfl_xor(v, off);
    return v;
}
__device__ __forceinline__ float wmax(float v) {
    #pragma unroll
    for (int off = 32; off; off >>= 1) v = fmaxf(v, __shfl_xor(v, off));
    return v;
}
__device__ __forceinline__ float sigm(float x) { return 1.f / (1.f + __expf(-x)); }
__device__ __forceinline__ float ftanh(float x) { return 1.f - 2.f / (__expf(2.f * x) + 1.f); }
// wave-broadcast: lane idx is uniform loop var -> v_readlane
__device__ __forceinline__ float bcast(float v, int l) {
    return __int_as_float(__builtin_amdgcn_readlane(__float_as_int(v), l));
}
__device__ __forceinline__ unsigned short f2bf(float f) {  // RNE
    unsigned u = __float_as_uint(f);
    u += 0x7FFFu + ((u >> 16) & 1u);
    return (unsigned short)(u >> 16);
}
__device__ __forceinline__ float bf2f(unsigned short s) {
    return __uint_as_float((unsigned)s << 16);
}

// ---------------- P0: supports matrix A = 0.5*(adj_n + softmax(relu(E E^T))) ----------------
__global__ void A_kernel(const float* __restrict__ adj, const float* __restrict__ nemb,
                         float* __restrict__ A) {
    const int n = blockIdx.x;
    const int lane = threadIdx.x; // 64
    float en[E_];
    #pragma unroll
    for (int d = 0; d < E_; ++d) en[d] = nemb[n * E_ + d];
    float asum = 0.f;
    for (int m = lane; m < N_; m += 64) asum += adj[n * N_ + m];
    asum = fmaxf(wsum(asum), 1e-6f);
    float g[5]; bool valid[5];
    float mx = -1e30f;
    #pragma unroll
    for (int it = 0; it < 5; ++it) {
        int m = lane + it * 64;
        valid[it] = (m < N_);
        float dt = 0.f;
        if (valid[it]) {
            #pragma unroll
            for (int e = 0; e < E_; ++e) dt += en[e] * nemb[m * E_ + e];
            dt = fmaxf(dt, 0.f);
            mx = fmaxf(mx, dt);
        }
        g[it] = dt;
    }
    mx = wmax(mx);
    float se = 0.f;
    #pragma unroll
    for (int it = 0; it < 5; ++it)
        if (valid[it]) { g[it] = __expf(g[it] - mx); se += g[it]; }
    se = wsum(se);
    float inv = 1.f / se;
    #pragma unroll
    for (int it = 0; it < 5; ++it) {
        int m = lane + it * 64;
        if (valid[it]) A[n * N_ + m] = 0.5f * (adj[n * N_ + m] / asum + g[it] * inv);
    }
}

// ---------------- P1 fused: all per-node generated weights + W12, one launch ----------------
__device__ __forceinline__ float embdot(const float* __restrict__ nemb, int n,
                                        const float* __restrict__ pool, int Q, int q) {
    float a = 0.f;
    #pragma unroll
    for (int d = 0; d < E_; ++d) a += nemb[n * E_ + d] * pool[d * Q + q];
    return a;
}

__global__ __launch_bounds__(256) void gen_kernel(
    const float* __restrict__ nemb,
    const float* __restrict__ gWp, const float* __restrict__ gbp,
    const float* __restrict__ uWp, const float* __restrict__ ubp,
    const float* __restrict__ mwp,
    const float* __restrict__ W1, const float* __restrict__ W2,
    float* __restrict__ gW, float* __restrict__ gb,
    float* __restrict__ uW, float* __restrict__ ub,
    float* __restrict__ wh_t, float* __restrict__ W12) {
    const int e0 = N_ * QG_;          // gate_W
    const int e1 = e0 + N_ * GO_;     // gate_b
    const int e2 = e1 + N_ * QU_;     // upd_W
    const int e3 = e2 + N_ * UO_;     // upd_b
    const int e4 = e3 + N_ * H_;      // wh (transposed store)
    const int e5 = e4 + H_ * E_;      // W12
    int idx = blockIdx.x * 256 + threadIdx.x;
    if (idx < e0) {
        int n = idx / QG_, q = idx % QG_;
        gW[idx] = embdot(nemb, n, gWp, QG_, q);
    } else if (idx < e1) {
        int i = idx - e0; int n = i / GO_, q = i % GO_;
        gb[i] = embdot(nemb, n, gbp, GO_, q);
    } else if (idx < e2) {
        int i = idx - e1; int n = i / QU_, q = i % QU_;
        uW[i] = embdot(nemb, n, uWp, QU_, q);
    } else if (idx < e3) {
        int i = idx - e2; int n = i / UO_, q = i % UO_;
        ub[i] = embdot(nemb, n, ubp, UO_, q);
    } else if (idx < e4) {
        int i = idx - e3; int n = i / H_, q = i % H_;
        wh_t[q * N_ + n] = embdot(nemb, n, mwp, H_, q);   // transposed: [j][n]
    } else if (idx < e5) {
        int i = idx - e4; int j = i / E_, e = i % E_;
        float a = 0.f;
        #pragma unroll
        for (int q = 0; q < HM_; ++q) a += W1[j * HM_ + q] * W2[q * E_ + e];
        W12[i] = a;
    }
}

// ---------------- P2: lane-parallel hypernet (no shuffles, no LDS) ----------------
__global__ __launch_bounds__(256) void hyper2_kernel(
    const float* __restrict__ hs, const float* __restrict__ src,
    const float* __restrict__ hyper_W, const float* __restrict__ hyper_b,
    const float* __restrict__ wh_t, const float* __restrict__ W12,
    float* __restrict__ x0, float* __restrict__ x1, float* __restrict__ emb) {
    const int tb = blockIdx.y;           // t*B + b
    const int t = tb / B_, b = tb % B_;
    const int n = blockIdx.x * 256 + threadIdx.x;
    const bool act = (n < N_);
    const int nc = act ? n : N_ - 1;
    float hsv[CH_];
    #pragma unroll
    for (int c = 0; c < CH_; ++c)
        hsv[c] = hs[((b * CH_ + c) * T_ + t) * N_ + nc];   // coalesced over n
    float ax0 = 0.f;
    float ae[E_] = {};
    #pragma unroll 8
    for (int j = 0; j < H_; ++j) {
        float hj = hyper_b[j];                              // uniform (scalar)
        #pragma unroll
        for (int c = 0; c < CH_; ++c) hj = fmaf(hsv[c], hyper_W[c * H_ + j], hj);
        hj = ftanh(hj);
        ax0 = fmaf(hj, wh_t[j * N_ + nc], ax0);             // coalesced over n
        #pragma unroll
        for (int e = 0; e < E_; ++e) ae[e] = fmaf(hj, W12[j * E_ + e], ae[e]);
    }
    if (act) {
        const int tbn = tb * N_ + n;
        x0[tbn] = ax0;
        x1[tbn] = src[(b * T_ + t) * N_ + n];
        #pragma unroll
        for (int e = 0; e < E_; ++e) emb[e * TBN_ + tbn] = ae[e];  // SoA, coalesced
    }
}

// ---------------- per-step: Wm (bf16, padded rows) + dmask + aggx ----------------
__global__ __launch_bounds__(256) void wm_kernel(
    const float* __restrict__ A, const float* __restrict__ emb,
    const float* __restrict__ nemb, const float* __restrict__ x0,
    const float* __restrict__ x1, unsigned short* __restrict__ Wm,
    float* __restrict__ dmask, float* __restrict__ aggx, int t) {
    const int wid = __builtin_amdgcn_readfirstlane(blockIdx.x * 4 + (threadIdx.x >> 6));
    const int lane = threadIdx.x & 63;
    const int b = wid / N_;
    const int n = wid % N_;
    const int tbn = (t * B_ + b) * N_ + n;
    const int xb = tbn - n; // (t*B+b)*N
    float et[E_];
    #pragma unroll
    for (int d = 0; d < E_; ++d) et[d] = emb[(size_t)d * TBN_ + tbn];  // SoA broadcast
    unsigned short* wr = Wm + (size_t)(b * N_ + n) * WMP_;
    float a0 = 0.f, a1 = 0.f;
    #pragma unroll
    for (int c = 0; c < 5; ++c) {
        int m = c * 64 + lane;
        bool v = (m < N_);
        int mc = v ? m : 0;
        float dt = 0.f;
        #pragma unroll
        for (int d = 0; d < E_; ++d) dt += et[d] * nemb[mc * E_ + d];
        float sg = sigm(dt);
        float w = v ? A[n * N_ + mc] * sg : 0.f;
        wr[m] = v ? f2bf(w) : (unsigned short)0;   // zero-pad m>=307
        if (v) {
            if (m == n) dmask[tbn] = sg;
            a0 += w * x0[xb + mc];
            a1 += w * x1[xb + mc];
        }
    }
    a0 = wsum(a0);
    a1 = wsum(a1);
    if (lane == 0) {
        aggx[(size_t)tbn * 2] = a0;
        aggx[(size_t)tbn * 2 + 1] = a1;
    }
}

// ---------------- per-step v4: aggS = Wm(bf16) x Sin, chunk-staged LDS (32KB) ----------------
__global__ __launch_bounds__(512) void aggS_kernel(
    const unsigned short* __restrict__ Wm, const float* __restrict__ Sin,
    float* __restrict__ aggS) {
    __shared__ float s_lds[128 * 64]; // 32 KB -> 4 blocks/CU
    const int tid = threadIdx.x;
    const int lane = tid & 63;
    const int wv = tid >> 6;
    const int b = blockIdx.y;
    const int nb = blockIdx.x * 32 + wv * 4;
    int roff[4];
    #pragma unroll
    for (int r = 0; r < 4; ++r) {
        int nr = nb + r; if (nr > N_ - 1) nr = N_ - 1;
        roff[r] = __builtin_amdgcn_readfirstlane((b * N_ + nr) * WMP_);
    }
    float acc[4] = {0.f, 0.f, 0.f, 0.f};
    const float4* s4 = (const float4*)(Sin + (size_t)b * N_ * 64);
    float4* d4 = (float4*)s_lds;
    #pragma unroll
    for (int sck = 0; sck < 3; ++sck) {
        const int mbase = sck * 128;
        const int nrows = (sck < 2) ? 128 : 64;   // sck2: rows 256..319 (>=307 clamped, w=0)
        if (sck) __syncthreads();
        for (int idx = tid; idx < nrows * 16; idx += 512) {
            int row = mbase + (idx >> 4);
            int rc = (row < N_) ? row : N_ - 1;
            d4[idx] = s4[rc * 16 + (idx & 15)];
        }
        __syncthreads();
        for (int sub = 0; sub < nrows; sub += 64) {
            const int m0 = mbase + sub;
            float wf0 = bf2f(Wm[roff[0] + m0 + lane]);
            float wf1 = bf2f(Wm[roff[1] + m0 + lane]);
            float wf2 = bf2f(Wm[roff[2] + m0 + lane]);
            float wf3 = bf2f(Wm[roff[3] + m0 + lane]);
            #pragma unroll 8
            for (int mm = 0; mm < 64; ++mm) {
                float sv = s_lds[(sub + mm) * 64 + lane];
                acc[0] = fmaf(bcast(wf0, mm), sv, acc[0]);
                acc[1] = fmaf(bcast(wf1, mm), sv, acc[1]);
                acc[2] = fmaf(bcast(wf2, mm), sv, acc[2]);
                acc[3] = fmaf(bcast(wf3, mm), sv, acc[3]);
            }
        }
    }
    #pragma unroll
    for (int r = 0; r < 4; ++r) {
        int nr = nb + r;
        if (nr < N_) aggS[((size_t)b * N_ + nr) * 64 + lane] = acc[r];
    }
}

// ---------------- per-step: gate matmul (all 64 b per block) -> zs, r ----------------
__global__ __launch_bounds__(256) void gate_mm_kernel(
    const float* __restrict__ gate_W, const float* __restrict__ gate_b,
    const float* __restrict__ x0, const float* __restrict__ x1,
    const float* __restrict__ S, const float* __restrict__ dmask,
    const float* __restrict__ aggx, const float* __restrict__ aggS,
    float* __restrict__ zs, float* __restrict__ rbuf, int t) {
    __shared__ float W_s[132][64];
    __shared__ float xg_s[64][132];
    const int oh = blockIdx.x, n = blockIdx.y;
    const int tid = threadIdx.x;
    for (int idx = tid; idx < 132 * 64; idx += 256) {
        int row = idx >> 6, op = idx & 63;
        int col = (op < 32) ? (oh * 32 + op) : (64 + oh * 32 + (op - 32));
        W_s[row][op] = gate_W[(n * 132 + row) * GO_ + col];
    }
    for (int idx = tid; idx < 64 * 132; idx += 256) {
        int b = idx / 132, i = idx % 132;
        int tb = (t * B_ + b) * N_ + n;
        float v;
        if (i < 66) {
            float xs = (i == 0) ? x0[tb] : (i == 1) ? x1[tb] : S[(b * N_ + n) * 64 + (i - 2)];
            v = dmask[tb] * xs;
        } else {
            int i2 = i - 66;
            v = (i2 < 2) ? aggx[(size_t)tb * 2 + i2] : aggS[(b * N_ + n) * 64 + (i2 - 2)];
        }
        xg_s[b][i] = v;
    }
    __syncthreads();
    const int bl = (tid >> 3) * 2, og = tid & 7;
    float acc[2][8] = {};
    for (int i = 0; i < 132; ++i) {
        float xv0 = xg_s[bl][i], xv1 = xg_s[bl + 1][i];
        #pragma unroll
        for (int r = 0; r < 8; ++r) {
            float wv = W_s[i][og * 8 + r];
            acc[0][r] = fmaf(xv0, wv, acc[0][r]);
            acc[1][r] = fmaf(xv1, wv, acc[1][r]);
        }
    }
    __syncthreads();
    float* zr_s = &xg_s[0][0];  // reuse as [64][64]
    #pragma unroll
    for (int q = 0; q < 2; ++q) {
        #pragma unroll
        for (int r = 0; r < 8; ++r) {
            int op = og * 8 + r;
            int col = (op < 32) ? (oh * 32 + op) : (64 + oh * 32 + (op - 32));
            zr_s[(bl + q) * 64 + op] = sigm(acc[q][r] + gate_b[n * GO_ + col]);
        }
    }
    __syncthreads();
    for (int idx = tid; idx < 64 * 32; idx += 256) {
        int b = idx >> 5, jl = idx & 31;
        int j = oh * 32 + jl;
        float z = zr_s[b * 64 + jl];
        float rr = zr_s[b * 64 + 32 + jl];
        int sidx = (b * N_ + n) * 64 + j;
        zs[sidx] = z * S[sidx];
        rbuf[sidx] = rr;
    }
}

// ---------------- per-step: update matmul (all 64 b per block) + state update ----------------
__global__ __launch_bounds__(256) void upd_mm_kernel(
    const float* __restrict__ upd_W, const float* __restrict__ upd_b,
    const float* __restrict__ x0, const float* __restrict__ x1,
    const float* __restrict__ zsrc, const float* __restrict__ dmask,
    const float* __restrict__ aggx, const float* __restrict__ aggS,
    const float* __restrict__ rbuf, float* __restrict__ S, int t) {
    __shared__ float W_s[132][64];
    __shared__ float xg_s[64][132];
    const int n = blockIdx.x;
    const int tid = threadIdx.x;
    for (int idx = tid; idx < 132 * 64; idx += 256) {
        int row = idx >> 6, op = idx & 63;
        W_s[row][op] = upd_W[(n * 132 + row) * UO_ + op];
    }
    for (int idx = tid; idx < 64 * 132; idx += 256) {
        int b = idx / 132, i = idx % 132;
        int tb = (t * B_ + b) * N_ + n;
        float v;
        if (i < 66) {
            float xs = (i == 0) ? x0[tb] : (i == 1) ? x1[tb] : zsrc[(b * N_ + n) * 64 + (i - 2)];
            v = dmask[tb] * xs;
        } else {
            int i2 = i - 66;
            v = (i2 < 2) ? aggx[(size_t)tb * 2 + i2] : aggS[(b * N_ + n) * 64 + (i2 - 2)];
        }
        xg_s[b][i] = v;
    }
    __syncthreads();
    const int bl = (tid >> 3) * 2, og = tid & 7;
    float acc[2][8] = {};
    for (int i = 0; i < 132; ++i) {
        float xv0 = xg_s[bl][i], xv1 = xg_s[bl + 1][i];
        #pragma unroll
        for (int r = 0; r < 8; ++r) {
            float wv = W_s[i][og * 8 + r];
            acc[0][r] = fmaf(xv0, wv, acc[0][r]);
            acc[1][r] = fmaf(xv1, wv, acc[1][r]);
        }
    }
    #pragma unroll
    for (int q = 0; q < 2; ++q) {
        int b = bl + q;
        #pragma unroll
        for (int r = 0; r < 8; ++r) {
            int op = og * 8 + r;
            float hc = ftanh(acc[q][r] + upd_b[n * UO_ + op]);
            int sidx = (b * N_ + n) * 64 + op;
            float rr = rbuf[sidx];
            float sv = S[sidx];
            S[sidx] = rr * sv + (1.f - rr) * hc;
        }
    }
}

// ---------------- final: layernorm + end linear ----------------
__global__ __launch_bounds__(256) void final_kernel(
    const float* __restrict__ S, const float* __restrict__ gamma,
    const float* __restrict__ beta, const float* __restrict__ endW,
    const float* __restrict__ endb, float* __restrict__ out) {
    const int wid = blockIdx.x * 4 + (threadIdx.x >> 6);
    const int lane = threadIdx.x & 63;
    const int b = wid / N_, n = wid % N_;
    float s = S[wid * 64 + lane];
    float mu = wsum(s) * (1.f / 64.f);
    float d = s - mu;
    float var = wsum(d * d) * (1.f / 64.f);
    float xn = d / sqrtf(var + 1e-12f) * gamma[lane] + beta[lane];
    #pragma unroll
    for (int o = 0; o < 12; ++o) {
        float dot = wsum(xn * endW[o * 64 + lane]);
        if (lane == o) out[(b * 12 + o) * N_ + n] = dot + endb[o];
    }
}

extern "C" void kernel_launch(void* const* d_in, const int* in_sizes, int n_in,
                              void* d_out, int out_size, void* d_ws, size_t ws_size,
                              hipStream_t stream) {
    const float* hyper_source = (const float*)d_in[0];
    const float* source       = (const float*)d_in[1];
    const float* adj          = (const float*)d_in[2];
    const float* nemb         = (const float*)d_in[3];
    const float* mwpool       = (const float*)d_in[4];
    const float* hyper_W      = (const float*)d_in[5];
    const float* hyper_b      = (const float*)d_in[6];
    const float* mask_W1      = (const float*)d_in[7];
    const float* mask_W2      = (const float*)d_in[8];
    const float* gate_Wpool   = (const float*)d_in[9];
    const float* gate_bpool   = (const float*)d_in[10];
    const float* upd_Wpool    = (const float*)d_in[11];
    const float* upd_bpool    = (const float*)d_in[12];
    const float* ln_gamma     = (const float*)d_in[13];
    const float* ln_beta      = (const float*)d_in[14];
    const float* end_W        = (const float*)d_in[15];
    const float* end_b        = (const float*)d_in[16];
    float* out = (float*)d_out;

    float* ws = (float*)d_ws;
    size_t off = 0;
    auto alloc = [&](size_t nf) {
        float* p = ws + off;
        off += (nf + 255) & ~(size_t)255;
        return p;
    };
    float* A      = alloc((size_t)N_ * N_);
    float* wh_t   = alloc((size_t)N_ * H_);
    float* W12    = alloc((size_t)H_ * E_);
    float* gate_W = alloc((size_t)N_ * QG_);
    float* gate_b = alloc((size_t)N_ * GO_);
    float* upd_W  = alloc((size_t)N_ * QU_);
    float* upd_b  = alloc((size_t)N_ * UO_);
    float* x0     = alloc((size_t)TBN_);
    float* x1     = alloc((size_t)TBN_);
    float* emb    = alloc((size_t)TBN_ * E_);   // SoA: [e][tbn]
    float* dmask  = alloc((size_t)TBN_);
    float* aggx   = alloc((size_t)TBN_ * 2);
    float* S      = alloc((size_t)B_ * N_ * H_);
    float* zs     = alloc((size_t)B_ * N_ * H_);
    float* rbuf   = alloc((size_t)B_ * N_ * H_);
    float* aggS   = alloc((size_t)B_ * N_ * H_);
    unsigned short* Wm = (unsigned short*)alloc((size_t)B_ * N_ * WMP_ / 2);  // bf16, 12.6 MB

    hipMemsetAsync(S, 0, (size_t)B_ * N_ * H_ * sizeof(float), stream);

    A_kernel<<<N_, 64, 0, stream>>>(adj, nemb, A);

    const int gen_total = N_ * QG_ + N_ * GO_ + N_ * QU_ + N_ * UO_ + N_ * H_ + H_ * E_;
    gen_kernel<<<(gen_total + 255) / 256, 256, 0, stream>>>(
        nemb, gate_Wpool, gate_bpool, upd_Wpool, upd_bpool, mwpool, mask_W1, mask_W2,
        gate_W, gate_b, upd_W, upd_b, wh_t, W12);

    hyper2_kernel<<<dim3(2, T_ * B_), 256, 0, stream>>>(hyper_source, source, hyper_W,
                                                        hyper_b, wh_t, W12, x0, x1, emb);

    for (int t = 0; t < T_; ++t) {
        wm_kernel<<<(B_ * N_) / 4, 256, 0, stream>>>(A, emb, nemb, x0, x1, Wm, dmask, aggx, t);
        aggS_kernel<<<dim3(10, B_), 512, 0, stream>>>(Wm, S, aggS);
        gate_mm_kernel<<<dim3(2, N_), 256, 0, stream>>>(gate_W, gate_b, x0, x1, S, dmask,
                                                        aggx, aggS, zs, rbuf, t);
        aggS_kernel<<<dim3(10, B_), 512, 0, stream>>>(Wm, zs, aggS);
        upd_mm_kernel<<<N_, 256, 0, stream>>>(upd_W, upd_b, x0, x1, zs, dmask, aggx,
                                              aggS, rbuf, S, t);
    }

    final_kernel<<<(B_ * N_) / 4, 256, 0, stream>>>(S, ln_gamma, ln_beta, end_W, end_b, out);
}

// Round 8
// 2459.581 us; speedup vs baseline: 1.0666x; 1.0666x over previous
//
#include <hip/hip_runtime.h>
#include <hip/hip_bf16.h>

#define N_ 307
#define B_ 64
#define T_ 12
#define H_ 64
#define E_ 10
#define CH_ 14
#define HM_ 16
#define I2_ 66   // 2*DIN + H
#define GO_ 128  // 2*H
#define UO_ 64
#define QG_ (2 * I2_ * GO_)  // 16896
#define QU_ (2 * I2_ * UO_)  // 8448
#define TBN_ (T_ * B_ * N_)  // 235776
#define WMP_ 320             // Wm row padded length (bf16)
#define XLD_ 67              // xgT leading-dim pad (conflict-free)

__device__ __forceinline__ float wsum(float v) {
    #pragma unroll
    for (int off = 32; off; off >>= 1) v += __shfl_xor(v, off);
    return v;
}
__device__ __forceinline__ float wmax(float v) {
    #pragma unroll
    for (int off = 32; off; off >>= 1) v = fmaxf(v, __shfl_xor(v, off));
    return v;
}
__device__ __forceinline__ float sigm(float x) { return 1.f / (1.f + __expf(-x)); }
__device__ __forceinline__ float ftanh(float x) { return 1.f - 2.f / (__expf(2.f * x) + 1.f); }
// wave-broadcast: lane idx is uniform loop var -> v_readlane
__device__ __forceinline__ float bcast(float v, int l) {
    return __int_as_float(__builtin_amdgcn_readlane(__float_as_int(v), l));
}
__device__ __forceinline__ unsigned short f2bf(float f) {  // RNE
    unsigned u = __float_as_uint(f);
    u += 0x7FFFu + ((u >> 16) & 1u);
    return (unsigned short)(u >> 16);
}
__device__ __forceinline__ float bf2f(unsigned short s) {
    return __uint_as_float((unsigned)s << 16);
}

// ---------------- P0: supports matrix A = 0.5*(adj_n + softmax(relu(E E^T))) ----------------
__global__ void A_kernel(const float* __restrict__ adj, const float* __restrict__ nemb,
                         float* __restrict__ A) {
    const int n = blockIdx.x;
    const int lane = threadIdx.x; // 64
    float en[E_];
    #pragma unroll
    for (int d = 0; d < E_; ++d) en[d] = nemb[n * E_ + d];
    float asum = 0.f;
    for (int m = lane; m < N_; m += 64) asum += adj[n * N_ + m];
    asum = fmaxf(wsum(asum), 1e-6f);
    float g[5]; bool valid[5];
    float mx = -1e30f;
    #pragma unroll
    for (int it = 0; it < 5; ++it) {
        int m = lane + it * 64;
        valid[it] = (m < N_);
        float dt = 0.f;
        if (valid[it]) {
            #pragma unroll
            for (int e = 0; e < E_; ++e) dt += en[e] * nemb[m * E_ + e];
            dt = fmaxf(dt, 0.f);
            mx = fmaxf(mx, dt);
        }
        g[it] = dt;
    }
    mx = wmax(mx);
    float se = 0.f;
    #pragma unroll
    for (int it = 0; it < 5; ++it)
        if (valid[it]) { g[it] = __expf(g[it] - mx); se += g[it]; }
    se = wsum(se);
    float inv = 1.f / se;
    #pragma unroll
    for (int it = 0; it < 5; ++it) {
        int m = lane + it * 64;
        if (valid[it]) A[n * N_ + m] = 0.5f * (adj[n * N_ + m] / asum + g[it] * inv);
    }
}

// ---------------- P1 fused: all per-node generated weights + W12, one launch ----------------
__device__ __forceinline__ float embdot(const float* __restrict__ nemb, int n,
                                        const float* __restrict__ pool, int Q, int q) {
    float a = 0.f;
    #pragma unroll
    for (int d = 0; d < E_; ++d) a += nemb[n * E_ + d] * pool[d * Q + q];
    return a;
}

__global__ __launch_bounds__(256) void gen_kernel(
    const float* __restrict__ nemb,
    const float* __restrict__ gWp, const float* __restrict__ gbp,
    const float* __restrict__ uWp, const float* __restrict__ ubp,
    const float* __restrict__ mwp,
    const float* __restrict__ W1, const float* __restrict__ W2,
    float* __restrict__ gW, float* __restrict__ gb,
    float* __restrict__ uW, float* __restrict__ ub,
    float* __restrict__ wh_t, float* __restrict__ W12) {
    const int e0 = N_ * QG_;          // gate_W
    const int e1 = e0 + N_ * GO_;     // gate_b
    const int e2 = e1 + N_ * QU_;     // upd_W
    const int e3 = e2 + N_ * UO_;     // upd_b
    const int e4 = e3 + N_ * H_;      // wh (transposed store)
    const int e5 = e4 + H_ * E_;      // W12
    int idx = blockIdx.x * 256 + threadIdx.x;
    if (idx < e0) {
        int n = idx / QG_, q = idx % QG_;
        gW[idx] = embdot(nemb, n, gWp, QG_, q);
    } else if (idx < e1) {
        int i = idx - e0; int n = i / GO_, q = i % GO_;
        gb[i] = embdot(nemb, n, gbp, GO_, q);
    } else if (idx < e2) {
        int i = idx - e1; int n = i / QU_, q = i % QU_;
        uW[i] = embdot(nemb, n, uWp, QU_, q);
    } else if (idx < e3) {
        int i = idx - e2; int n = i / UO_, q = i % UO_;
        ub[i] = embdot(nemb, n, ubp, UO_, q);
    } else if (idx < e4) {
        int i = idx - e3; int n = i / H_, q = i % H_;
        wh_t[q * N_ + n] = embdot(nemb, n, mwp, H_, q);   // transposed: [j][n]
    } else if (idx < e5) {
        int i = idx - e4; int j = i / E_, e = i % E_;
        float a = 0.f;
        #pragma unroll
        for (int q = 0; q < HM_; ++q) a += W1[j * HM_ + q] * W2[q * E_ + e];
        W12[i] = a;
    }
}

// ---------------- P2: lane-parallel hypernet (no shuffles, no LDS) ----------------
__global__ __launch_bounds__(256) void hyper2_kernel(
    const float* __restrict__ hs, const float* __restrict__ src,
    const float* __restrict__ hyper_W, const float* __restrict__ hyper_b,
    const float* __restrict__ wh_t, const float* __restrict__ W12,
    float* __restrict__ x0, float* __restrict__ x1, float* __restrict__ emb) {
    const int tb = blockIdx.y;           // t*B + b
    const int t = tb / B_, b = tb % B_;
    const int n = blockIdx.x * 256 + threadIdx.x;
    const bool act = (n < N_);
    const int nc = act ? n : N_ - 1;
    float hsv[CH_];
    #pragma unroll
    for (int c = 0; c < CH_; ++c)
        hsv[c] = hs[((b * CH_ + c) * T_ + t) * N_ + nc];   // coalesced over n
    float ax0 = 0.f;
    float ae[E_] = {};
    #pragma unroll 8
    for (int j = 0; j < H_; ++j) {
        float hj = hyper_b[j];                              // uniform (scalar)
        #pragma unroll
        for (int c = 0; c < CH_; ++c) hj = fmaf(hsv[c], hyper_W[c * H_ + j], hj);
        hj = ftanh(hj);
        ax0 = fmaf(hj, wh_t[j * N_ + nc], ax0);             // coalesced over n
        #pragma unroll
        for (int e = 0; e < E_; ++e) ae[e] = fmaf(hj, W12[j * E_ + e], ae[e]);
    }
    if (act) {
        const int tbn = tb * N_ + n;
        x0[tbn] = ax0;
        x1[tbn] = src[(b * T_ + t) * N_ + n];
        #pragma unroll
        for (int e = 0; e < E_; ++e) emb[e * TBN_ + tbn] = ae[e];  // SoA, coalesced
    }
}

// ---------------- per-step: Wm (bf16, padded rows) + dmask + aggx ----------------
__global__ __launch_bounds__(256) void wm_kernel(
    const float* __restrict__ A, const float* __restrict__ emb,
    const float* __restrict__ nemb, const float* __restrict__ x0,
    const float* __restrict__ x1, unsigned short* __restrict__ Wm,
    float* __restrict__ dmask, float* __restrict__ aggx, int t) {
    const int wid = __builtin_amdgcn_readfirstlane(blockIdx.x * 4 + (threadIdx.x >> 6));
    const int lane = threadIdx.x & 63;
    const int b = wid / N_;
    const int n = wid % N_;
    const int tbn = (t * B_ + b) * N_ + n;
    const int xb = tbn - n; // (t*B+b)*N
    float et[E_];
    #pragma unroll
    for (int d = 0; d < E_; ++d) et[d] = emb[(size_t)d * TBN_ + tbn];  // SoA broadcast
    unsigned short* wr = Wm + (size_t)(b * N_ + n) * WMP_;
    float a0 = 0.f, a1 = 0.f;
    #pragma unroll
    for (int c = 0; c < 5; ++c) {
        int m = c * 64 + lane;
        bool v = (m < N_);
        int mc = v ? m : 0;
        float dt = 0.f;
        #pragma unroll
        for (int d = 0; d < E_; ++d) dt += et[d] * nemb[mc * E_ + d];
        float sg = sigm(dt);
        float w = v ? A[n * N_ + mc] * sg : 0.f;
        wr[m] = v ? f2bf(w) : (unsigned short)0;   // zero-pad m>=307
        if (v) {
            if (m == n) dmask[tbn] = sg;
            a0 += w * x0[xb + mc];
            a1 += w * x1[xb + mc];
        }
    }
    a0 = wsum(a0);
    a1 = wsum(a1);
    if (lane == 0) {
        aggx[(size_t)tbn * 2] = a0;
        aggx[(size_t)tbn * 2 + 1] = a1;
    }
}

// ---------------- per-step v4: aggS = Wm(bf16) x Sin, chunk-staged LDS (32KB) ----------------
__global__ __launch_bounds__(512) void aggS_kernel(
    const unsigned short* __restrict__ Wm, const float* __restrict__ Sin,
    float* __restrict__ aggS) {
    __shared__ float s_lds[128 * 64]; // 32 KB -> 4 blocks/CU
    const int tid = threadIdx.x;
    const int lane = tid & 63;
    const int wv = tid >> 6;
    const int b = blockIdx.y;
    const int nb = blockIdx.x * 32 + wv * 4;
    int roff[4];
    #pragma unroll
    for (int r = 0; r < 4; ++r) {
        int nr = nb + r; if (nr > N_ - 1) nr = N_ - 1;
        roff[r] = __builtin_amdgcn_readfirstlane((b * N_ + nr) * WMP_);
    }
    float acc[4] = {0.f, 0.f, 0.f, 0.f};
    const float4* s4 = (const float4*)(Sin + (size_t)b * N_ * 64);
    float4* d4 = (float4*)s_lds;
    #pragma unroll
    for (int sck = 0; sck < 3; ++sck) {
        const int mbase = sck * 128;
        const int nrows = (sck < 2) ? 128 : 64;   // sck2: rows 256..319 (>=307 clamped, w=0)
        if (sck) __syncthreads();
        for (int idx = tid; idx < nrows * 16; idx += 512) {
            int row = mbase + (idx >> 4);
            int rc = (row < N_) ? row : N_ - 1;
            d4[idx] = s4[rc * 16 + (idx & 15)];
        }
        __syncthreads();
        for (int sub = 0; sub < nrows; sub += 64) {
            const int m0 = mbase + sub;
            float wf0 = bf2f(Wm[roff[0] + m0 + lane]);
            float wf1 = bf2f(Wm[roff[1] + m0 + lane]);
            float wf2 = bf2f(Wm[roff[2] + m0 + lane]);
            float wf3 = bf2f(Wm[roff[3] + m0 + lane]);
            #pragma unroll 8
            for (int mm = 0; mm < 64; ++mm) {
                float sv = s_lds[(sub + mm) * 64 + lane];
                acc[0] = fmaf(bcast(wf0, mm), sv, acc[0]);
                acc[1] = fmaf(bcast(wf1, mm), sv, acc[1]);
                acc[2] = fmaf(bcast(wf2, mm), sv, acc[2]);
                acc[3] = fmaf(bcast(wf3, mm), sv, acc[3]);
            }
        }
    }
    #pragma unroll
    for (int r = 0; r < 4; ++r) {
        int nr = nb + r;
        if (nr < N_) aggS[((size_t)b * N_ + nr) * 64 + lane] = acc[r];
    }
}

// ---------------- per-step v3: gate matmul, X-stationary LDS, W streamed from L2 ----------------
// grid (2, N): oh=0 -> z cols 0..63 (writes zs=z*S), oh=1 -> r cols 64..127 (writes rbuf)
__global__ __launch_bounds__(256) void gate_mm_kernel(
    const float* __restrict__ gate_W, const float* __restrict__ gate_b,
    const float* __restrict__ x0, const float* __restrict__ x1,
    const float* __restrict__ S, const float* __restrict__ dmask,
    const float* __restrict__ aggx, const float* __restrict__ aggS,
    float* __restrict__ zs, float* __restrict__ rbuf, int t) {
    __shared__ float xgT[132 * XLD_];   // 35.4 KB
    const int oh = blockIdx.x, n = blockIdx.y;
    const int tid = threadIdx.x;
    for (int idx = tid; idx < 64 * 132; idx += 256) {
        int b = idx / 132, i = idx % 132;
        int tb = (t * B_ + b) * N_ + n;
        float v;
        if (i < 66) {
            float xs = (i == 0) ? x0[tb] : (i == 1) ? x1[tb] : S[(b * N_ + n) * 64 + (i - 2)];
            v = dmask[tb] * xs;
        } else {
            int i2 = i - 66;
            v = (i2 < 2) ? aggx[(size_t)tb * 2 + i2] : aggS[(b * N_ + n) * 64 + (i2 - 2)];
        }
        xgT[i * XLD_ + b] = v;
    }
    __syncthreads();
    const int b0 = (tid & 15) * 4;
    const int c0 = (tid >> 4) * 4;
    const float* wp = gate_W + (size_t)n * 132 * GO_ + oh * 64 + c0;
    float acc[4][4] = {};
    for (int i = 0; i < 132; ++i) {
        float4 xv = *(const float4*)&xgT[i * XLD_ + b0];
        float4 wv = *(const float4*)&wp[(size_t)i * GO_];
        float xa[4] = {xv.x, xv.y, xv.z, xv.w};
        float wa[4] = {wv.x, wv.y, wv.z, wv.w};
        #pragma unroll
        for (int bq = 0; bq < 4; ++bq)
            #pragma unroll
            for (int cq = 0; cq < 4; ++cq)
                acc[bq][cq] = fmaf(xa[bq], wa[cq], acc[bq][cq]);
    }
    const float* gb = gate_b + n * GO_ + oh * 64 + c0;
    float bias[4] = {gb[0], gb[1], gb[2], gb[3]};
    #pragma unroll
    for (int bq = 0; bq < 4; ++bq) {
        const int sbase = ((b0 + bq) * N_ + n) * 64 + c0;
        #pragma unroll
        for (int cq = 0; cq < 4; ++cq) {
            float g = sigm(acc[bq][cq] + bias[cq]);
            if (oh == 0) zs[sbase + cq] = g * S[sbase + cq];
            else         rbuf[sbase + cq] = g;
        }
    }
}

// ---------------- per-step v3: update matmul, X-stationary, W streamed; in-place S ----------------
// grid (2, N): oh splits the 64 output cols into 2x32
__global__ __launch_bounds__(256) void upd_mm_kernel(
    const float* __restrict__ upd_W, const float* __restrict__ upd_b,
    const float* __restrict__ x0, const float* __restrict__ x1,
    const float* __restrict__ zsrc, const float* __restrict__ dmask,
    const float* __restrict__ aggx, const float* __restrict__ aggS,
    const float* __restrict__ rbuf, float* __restrict__ S, int t) {
    __shared__ float xgT[132 * XLD_];
    const int oh = blockIdx.x, n = blockIdx.y;
    const int tid = threadIdx.x;
    for (int idx = tid; idx < 64 * 132; idx += 256) {
        int b = idx / 132, i = idx % 132;
        int tb = (t * B_ + b) * N_ + n;
        float v;
        if (i < 66) {
            float xs = (i == 0) ? x0[tb] : (i == 1) ? x1[tb] : zsrc[(b * N_ + n) * 64 + (i - 2)];
            v = dmask[tb] * xs;
        } else {
            int i2 = i - 66;
            v = (i2 < 2) ? aggx[(size_t)tb * 2 + i2] : aggS[(b * N_ + n) * 64 + (i2 - 2)];
        }
        xgT[i * XLD_ + b] = v;
    }
    __syncthreads();
    const int b0 = (tid & 15) * 4;
    const int c0 = (tid >> 4) * 2 + oh * 32;
    const float* wp = upd_W + (size_t)n * 132 * UO_ + c0;
    float acc[4][2] = {};
    for (int i = 0; i < 132; ++i) {
        float4 xv = *(const float4*)&xgT[i * XLD_ + b0];
        float2 wv = *(const float2*)&wp[(size_t)i * UO_];
        float xa[4] = {xv.x, xv.y, xv.z, xv.w};
        #pragma unroll
        for (int bq = 0; bq < 4; ++bq) {
            acc[bq][0] = fmaf(xa[bq], wv.x, acc[bq][0]);
            acc[bq][1] = fmaf(xa[bq], wv.y, acc[bq][1]);
        }
    }
    const float bias0 = upd_b[n * UO_ + c0];
    const float bias1 = upd_b[n * UO_ + c0 + 1];
    #pragma unroll
    for (int bq = 0; bq < 4; ++bq) {
        const int sbase = ((b0 + bq) * N_ + n) * 64 + c0;
        #pragma unroll
        for (int cq = 0; cq < 2; ++cq) {
            float hc = ftanh(acc[bq][cq] + (cq ? bias1 : bias0));
            float rr = rbuf[sbase + cq];
            float sv = S[sbase + cq];
            S[sbase + cq] = rr * sv + (1.f - rr) * hc;
        }
    }
}

// ---------------- final: layernorm + end linear ----------------
__global__ __launch_bounds__(256) void final_kernel(
    const float* __restrict__ S, const float* __restrict__ gamma,
    const float* __restrict__ beta, const float* __restrict__ endW,
    const float* __restrict__ endb, float* __restrict__ out) {
    const int wid = blockIdx.x * 4 + (threadIdx.x >> 6);
    const int lane = threadIdx.x & 63;
    const int b = wid / N_, n = wid % N_;
    float s = S[wid * 64 + lane];
    float mu = wsum(s) * (1.f / 64.f);
    float d = s - mu;
    float var = wsum(d * d) * (1.f / 64.f);
    float xn = d / sqrtf(var + 1e-12f) * gamma[lane] + beta[lane];
    #pragma unroll
    for (int o = 0; o < 12; ++o) {
        float dot = wsum(xn * endW[o * 64 + lane]);
        if (lane == o) out[(b * 12 + o) * N_ + n] = dot + endb[o];
    }
}

extern "C" void kernel_launch(void* const* d_in, const int* in_sizes, int n_in,
                              void* d_out, int out_size, void* d_ws, size_t ws_size,
                              hipStream_t stream) {
    const float* hyper_source = (const float*)d_in[0];
    const float* source       = (const float*)d_in[1];
    const float* adj          = (const float*)d_in[2];
    const float* nemb         = (const float*)d_in[3];
    const float* mwpool       = (const float*)d_in[4];
    const float* hyper_W      = (const float*)d_in[5];
    const float* hyper_b      = (const float*)d_in[6];
    const float* mask_W1      = (const float*)d_in[7];
    const float* mask_W2      = (const float*)d_in[8];
    const float* gate_Wpool   = (const float*)d_in[9];
    const float* gate_bpool   = (const float*)d_in[10];
    const float* upd_Wpool    = (const float*)d_in[11];
    const float* upd_bpool    = (const float*)d_in[12];
    const float* ln_gamma     = (const float*)d_in[13];
    const float* ln_beta      = (const float*)d_in[14];
    const float* end_W        = (const float*)d_in[15];
    const float* end_b        = (const float*)d_in[16];
    float* out = (float*)d_out;

    float* ws = (float*)d_ws;
    size_t off = 0;
    auto alloc = [&](size_t nf) {
        float* p = ws + off;
        off += (nf + 255) & ~(size_t)255;
        return p;
    };
    float* A      = alloc((size_t)N_ * N_);
    float* wh_t   = alloc((size_t)N_ * H_);
    float* W12    = alloc((size_t)H_ * E_);
    float* gate_W = alloc((size_t)N_ * QG_);
    float* gate_b = alloc((size_t)N_ * GO_);
    float* upd_W  = alloc((size_t)N_ * QU_);
    float* upd_b  = alloc((size_t)N_ * UO_);
    float* x0     = alloc((size_t)TBN_);
    float* x1     = alloc((size_t)TBN_);
    float* emb    = alloc((size_t)TBN_ * E_);   // SoA: [e][tbn]
    float* dmask  = alloc((size_t)TBN_);
    float* aggx   = alloc((size_t)TBN_ * 2);
    float* S      = alloc((size_t)B_ * N_ * H_);
    float* zs     = alloc((size_t)B_ * N_ * H_);
    float* rbuf   = alloc((size_t)B_ * N_ * H_);
    float* aggS   = alloc((size_t)B_ * N_ * H_);
    unsigned short* Wm = (unsigned short*)alloc((size_t)B_ * N_ * WMP_ / 2);  // bf16, 12.6 MB

    hipMemsetAsync(S, 0, (size_t)B_ * N_ * H_ * sizeof(float), stream);

    A_kernel<<<N_, 64, 0, stream>>>(adj, nemb, A);

    const int gen_total = N_ * QG_ + N_ * GO_ + N_ * QU_ + N_ * UO_ + N_ * H_ + H_ * E_;
    gen_kernel<<<(gen_total + 255) / 256, 256, 0, stream>>>(
        nemb, gate_Wpool, gate_bpool, upd_Wpool, upd_bpool, mwpool, mask_W1, mask_W2,
        gate_W, gate_b, upd_W, upd_b, wh_t, W12);

    hyper2_kernel<<<dim3(2, T_ * B_), 256, 0, stream>>>(hyper_source, source, hyper_W,
                                                        hyper_b, wh_t, W12, x0, x1, emb);

    for (int t = 0; t < T_; ++t) {
        wm_kernel<<<(B_ * N_) / 4, 256, 0, stream>>>(A, emb, nemb, x0, x1, Wm, dmask, aggx, t);
        aggS_kernel<<<dim3(10, B_), 512, 0, stream>>>(Wm, S, aggS);
        gate_mm_kernel<<<dim3(2, N_), 256, 0, stream>>>(gate_W, gate_b, x0, x1, S, dmask,
                                                        aggx, aggS, zs, rbuf, t);
        aggS_kernel<<<dim3(10, B_), 512, 0, stream>>>(Wm, zs, aggS);
        upd_mm_kernel<<<dim3(2, N_), 256, 0, stream>>>(upd_W, upd_b, x0, x1, zs, dmask, aggx,
                                                       aggS, rbuf, S, t);
    }

    final_kernel<<<(B_ * N_) / 4, 256, 0, stream>>>(S, ln_gamma, ln_beta, end_W, end_b, out);
}